// Round 12
// baseline (301.146 us; speedup 1.0000x reference)
//
#include <hip/hip_runtime.h>
#include <hip/hip_bf16.h>
#include <math.h>

typedef __attribute__((ext_vector_type(8))) short bf16x8;
typedef __attribute__((ext_vector_type(4))) float f32x4;
typedef __attribute__((ext_vector_type(2))) __fp16 f16x2;
typedef __attribute__((ext_vector_type(4))) unsigned int u32x4;
typedef __attribute__((ext_vector_type(2))) unsigned int u32x2;

constexpr int NB = 16, NQ = 4096, LF = 2048, C = 256;

__device__ __forceinline__ unsigned short bfbits(float x) {
    return __builtin_bit_cast(unsigned short, __float2bfloat16(x));
}
__device__ __forceinline__ unsigned pk2(float a, float b) {
    return (unsigned)bfbits(a) | ((unsigned)bfbits(b) << 16);
}
__device__ __forceinline__ float bflo(unsigned d) { return __builtin_bit_cast(float, d << 16); }
__device__ __forceinline__ float bfhi(unsigned d) { return __builtin_bit_cast(float, d & 0xffff0000u); }

// ---- prep: weights -> bf16 fragment-linear layout in ws (verified) ----
// frag stride 1024 B, lane at +l*16. 8 KiB sub-chunk s = frags s*8..s*8+7.
// subs: 0-3=w1c1(nt), 4-7=w1c2, 8-11=w2c1, 12-15=w2c2, 16-47=gw1 (nt*2+half)
__global__ void prep_weights(const float* __restrict__ c1w1, const float* __restrict__ c2w1,
                             const float* __restrict__ c1w2, const float* __restrict__ c2w2,
                             const float* __restrict__ gw1, unsigned short* __restrict__ ws)
{
    int t = blockIdx.x * 256 + threadIdx.x;          // 0..24575
    const float* src; int K, nks, dstoff, f;
    if (t < 2048)      { src = c1w1; K = 256; nks = 8;  dstoff = 0;      f = t; }
    else if (t < 4096) { src = c2w1; K = 256; nks = 8;  dstoff = 16384;  f = t - 2048; }
    else if (t < 6144) { src = c1w2; K = 64;  nks = 2;  dstoff = 32768;  f = t - 4096; }
    else if (t < 8192) { src = c2w2; K = 64;  nks = 2;  dstoff = 49152;  f = t - 6144; }
    else               { src = gw1;  K = 512; nks = 16; dstoff = 65536;  f = t - 8192; }
    int l = f & 63, s = f >> 6;
    int nt = s / nks, ks = s % nks;
    int n  = nt * 16 + (l & 15);
    int k0 = ks * 32 + (l >> 4) * 8;
    unsigned short* d = ws + dstoff + (size_t)f * 8;
    const float* sp = src + (size_t)n * K + k0;
    #pragma unroll
    for (int e = 0; e < 8; ++e) d[e] = bfbits(sp[e]);
}

// stage one 8 KiB sub-chunk with 128 threads (2 waves): 4 loads of 16 B per lane
__device__ __forceinline__ void stage_sub(const unsigned short* wsb, int sub,
                                          unsigned short* dst, int wid, int l)
{
    const char* g = (const char*)wsb + (size_t)sub * 8192 + (size_t)wid * 1024 + (size_t)l * 16;
    char* d = (char*)dst + wid * 1024;                 // wave-uniform; HW adds lane*16
    #pragma unroll
    for (int i = 0; i < 4; ++i) {
        __builtin_amdgcn_global_load_lds(
            (const __attribute__((address_space(1))) void*)(g + i * 2048),
            (__attribute__((address_space(3))) void*)(d + i * 2048),
            16, 0, 0);
    }
}

// ---- main: R10 structure + amdgpu_waves_per_eu(2,2) pinning 256-VGPR codegen ----
__global__ __launch_bounds__(128)
__attribute__((amdgpu_waves_per_eu(2, 2)))
void semalign_v12(const float* __restrict__ feat,  const float* __restrict__ qbox,
                  const float* __restrict__ qfeat, const float* __restrict__ posf,
                  const float* __restrict__ c1b1,  const float* __restrict__ c1b2,
                  const float* __restrict__ c1g,   const float* __restrict__ c1be,
                  const float* __restrict__ c2b1,  const float* __restrict__ c2b2,
                  const float* __restrict__ c2g,   const float* __restrict__ c2be,
                  const float* __restrict__ gb1,   const float* __restrict__ gw2,
                  const float* __restrict__ gb2,
                  const unsigned short* __restrict__ wsb,
                  float* __restrict__ out)
{
    __shared__ __align__(16) unsigned short sW[2][4096];     // 2 x 8 KiB weight dbuf
    __shared__ __align__(16) unsigned short sP[2][16][256];  // 2 x 8 KiB per-wave H/pooled

    const int tid = threadIdx.x, l = tid & 63, wid = tid >> 6;   // 2 waves
    const int lr = l & 15, lg = l >> 4;
    const int rowb = blockIdx.x * 32 + wid * 16;
    const int q = rowb >> 4;
    const int b = lr;
    const int swz = (lr & 7) << 4;

    stage_sub(wsb, 0, sW[0], wid, l);
    stage_sub(wsb, 1, sW[1], wid, l);

    const float* prow = posf  + ((size_t)b * NQ + q) * C;
    const float* qrow = qfeat + ((size_t)b * NQ + q) * C;
    float cx = qbox[((size_t)b * NQ + q) * 2 + 0];
    float w  = qbox[((size_t)b * NQ + q) * 2 + 1];
    float fs = fminf(fmaxf((cx - 0.5f * w) * (float)LF, 0.f), (float)(LF - 1));
    float fe = fminf(fmaxf((cx + 0.5f * w) * (float)LF, 0.f), (float)(LF - 1));
    const float* srow = feat + ((size_t)b * LF + (int)rintf(fs)) * C;
    const float* erow = feat + ((size_t)b * LF + (int)rintf(fe)) * C;

    // activation B-frags from global (overlaps with staging)
    bf16x8 v1f[8], v2f[8];
    #pragma unroll
    for (int ks = 0; ks < 8; ++ks) {
        int k0 = ks * 32 + lg * 8;
        float4 s0 = *(const float4*)(srow + k0), s1 = *(const float4*)(srow + k0 + 4);
        float4 e0 = *(const float4*)(erow + k0), e1 = *(const float4*)(erow + k0 + 4);
        float4 p0 = *(const float4*)(prow + k0), p1 = *(const float4*)(prow + k0 + 4);
        u32x4 a, c;
        a[0] = pk2(s0.x * p0.x, s0.y * p0.y); a[1] = pk2(s0.z * p0.z, s0.w * p0.w);
        a[2] = pk2(s1.x * p1.x, s1.y * p1.y); a[3] = pk2(s1.z * p1.z, s1.w * p1.w);
        c[0] = pk2(e0.x * p0.x, e0.y * p0.y); c[1] = pk2(e0.z * p0.z, e0.w * p0.w);
        c[2] = pk2(e1.x * p1.x, e1.y * p1.y); c[3] = pk2(e1.z * p1.z, e1.w * p1.w);
        v1f[ks] = __builtin_bit_cast(bf16x8, a);
        v2f[ks] = __builtin_bit_cast(bf16x8, c);
    }

    __syncthreads();                                  // subs 0,1 resident

    // ---------- subs 0..7: GEMM1 (c1 then c2), one nt per sub ----------
    f32x4 a1[4] = {}, a2[4] = {};
    #pragma unroll
    for (int ss = 0; ss < 8; ++ss) {
        const char* wb = (const char*)sW[ss & 1];
        int nt = ss & 3;
        #pragma unroll
        for (int ks = 0; ks < 8; ++ks) {
            bf16x8 wf = *(const bf16x8*)(wb + ks * 1024 + l * 16);
            if (ss < 4) a1[nt] = __builtin_amdgcn_mfma_f32_16x16x32_bf16(wf, v1f[ks], a1[nt], 0, 0, 0);
            else        a2[nt] = __builtin_amdgcn_mfma_f32_16x16x32_bf16(wf, v2f[ks], a2[nt], 0, 0, 0);
        }
        __syncthreads();
        stage_sub(wsb, ss + 2, sW[ss & 1], wid, l);
    }

    // H pack -> sP head, read H frags
    char* hb = (char*)&sP[wid][0][0];
    bf16x8 hA0, hA1, hB0, hB1;
    {
        #pragma unroll
        for (int nt = 0; nt < 4; ++nt) {
            float4 b1v = *(const float4*)(c1b1 + nt * 16 + lg * 4);
            float4 b2v = *(const float4*)(c2b1 + nt * 16 + lg * 4);
            u32x2 wv;
            wv[0] = pk2(fmaxf(a1[nt][0] + b1v.x, 0.f), fmaxf(a1[nt][1] + b1v.y, 0.f));
            wv[1] = pk2(fmaxf(a1[nt][2] + b1v.z, 0.f), fmaxf(a1[nt][3] + b1v.w, 0.f));
            *(u32x2*)(hb + lr * 128 + ((nt * 32 + lg * 8) ^ swz)) = wv;
            wv[0] = pk2(fmaxf(a2[nt][0] + b2v.x, 0.f), fmaxf(a2[nt][1] + b2v.y, 0.f));
            wv[1] = pk2(fmaxf(a2[nt][2] + b2v.z, 0.f), fmaxf(a2[nt][3] + b2v.w, 0.f));
            *(u32x2*)(hb + 2048 + lr * 128 + ((nt * 32 + lg * 8) ^ swz)) = wv;
        }
        asm volatile("s_waitcnt lgkmcnt(0)" ::: "memory");
        hA0 = *(const bf16x8*)(hb + lr * 128 + ((0  + lg * 16) ^ swz));
        hA1 = *(const bf16x8*)(hb + lr * 128 + ((64 + lg * 16) ^ swz));
        hB0 = *(const bf16x8*)(hb + 2048 + lr * 128 + ((0  + lg * 16) ^ swz));
        hB1 = *(const bf16x8*)(hb + 2048 + lr * 128 + ((64 + lg * 16) ^ swz));
    }

    // ---------- subs 8..11: GEMM2 c1 (4 nt per sub) ----------
    f16x2 Ph[16][2];
    {
        f32x4 u0[16] = {};
        #pragma unroll
        for (int ss = 0; ss < 4; ++ss) {
            const char* wb = (const char*)sW[ss & 1];
            #pragma unroll
            for (int i = 0; i < 4; ++i) {
                int nt = ss * 4 + i;
                bf16x8 w0 = *(const bf16x8*)(wb + (i * 2 + 0) * 1024 + l * 16);
                bf16x8 w1 = *(const bf16x8*)(wb + (i * 2 + 1) * 1024 + l * 16);
                u0[nt] = __builtin_amdgcn_mfma_f32_16x16x32_bf16(w0, hA0, u0[nt], 0, 0, 0);
                u0[nt] = __builtin_amdgcn_mfma_f32_16x16x32_bf16(w1, hA1, u0[nt], 0, 0, 0);
            }
            __syncthreads();
            stage_sub(wsb, 10 + ss, sW[ss & 1], wid, l);
        }
        float S = 0.f, Q2 = 0.f;
        #pragma unroll
        for (int nt = 0; nt < 16; ++nt) {
            float4 bv = *(const float4*)(c1b2 + nt * 16 + lg * 4);
            u0[nt][0] += bv.x; u0[nt][1] += bv.y; u0[nt][2] += bv.z; u0[nt][3] += bv.w;
            S  += u0[nt][0] + u0[nt][1] + u0[nt][2] + u0[nt][3];
            Q2 += u0[nt][0] * u0[nt][0] + u0[nt][1] * u0[nt][1]
                + u0[nt][2] * u0[nt][2] + u0[nt][3] * u0[nt][3];
        }
        S  += __shfl_xor(S, 16);  S  += __shfl_xor(S, 32);
        Q2 += __shfl_xor(Q2, 16); Q2 += __shfl_xor(Q2, 32);
        float mu  = S * (1.f / 256.f);
        float rsg = rsqrtf(Q2 * (1.f / 256.f) - mu * mu + 1e-6f);
        #pragma unroll
        for (int nt = 0; nt < 16; ++nt) {
            float4 gv  = *(const float4*)(c1g  + nt * 16 + lg * 4);
            float4 bev = *(const float4*)(c1be + nt * 16 + lg * 4);
            float4 xv  = *(const float4*)(srow + nt * 16 + lg * 4);
            float g4[4] = { gv.x, gv.y, gv.z, gv.w };
            float e4[4] = { bev.x, bev.y, bev.z, bev.w };
            float x4[4] = { xv.x, xv.y, xv.z, xv.w };
            float tm[4];
            #pragma unroll
            for (int r = 0; r < 4; ++r) {
                float ln = (u0[nt][r] - mu) * rsg * g4[r] + e4[r];
                float sg = 1.f / (1.f + __expf(-ln));
                tm[r] = 0.5f * sg * x4[r];
            }
            Ph[nt][0] = __builtin_amdgcn_cvt_pkrtz(tm[0], tm[1]);
            Ph[nt][1] = __builtin_amdgcn_cvt_pkrtz(tm[2], tm[3]);
        }
    }

    // ---------- subs 12..15: GEMM2 c2 (4 nt per sub) + LN2 -> pooled/qf frags ----------
    bf16x8 qff[8];
    {
        f32x4 u1[16] = {};
        #pragma unroll
        for (int ss = 0; ss < 4; ++ss) {
            const char* wb = (const char*)sW[ss & 1];
            #pragma unroll
            for (int i = 0; i < 4; ++i) {
                int nt = ss * 4 + i;
                bf16x8 w0 = *(const bf16x8*)(wb + (i * 2 + 0) * 1024 + l * 16);
                bf16x8 w1 = *(const bf16x8*)(wb + (i * 2 + 1) * 1024 + l * 16);
                u1[nt] = __builtin_amdgcn_mfma_f32_16x16x32_bf16(w0, hB0, u1[nt], 0, 0, 0);
                u1[nt] = __builtin_amdgcn_mfma_f32_16x16x32_bf16(w1, hB1, u1[nt], 0, 0, 0);
            }
            __syncthreads();
            stage_sub(wsb, 14 + ss, sW[ss & 1], wid, l);
        }
        float S = 0.f, Q2 = 0.f;
        #pragma unroll
        for (int nt = 0; nt < 16; ++nt) {
            float4 bv = *(const float4*)(c2b2 + nt * 16 + lg * 4);
            u1[nt][0] += bv.x; u1[nt][1] += bv.y; u1[nt][2] += bv.z; u1[nt][3] += bv.w;
            S  += u1[nt][0] + u1[nt][1] + u1[nt][2] + u1[nt][3];
            Q2 += u1[nt][0] * u1[nt][0] + u1[nt][1] * u1[nt][1]
                + u1[nt][2] * u1[nt][2] + u1[nt][3] * u1[nt][3];
        }
        S  += __shfl_xor(S, 16);  S  += __shfl_xor(S, 32);
        Q2 += __shfl_xor(Q2, 16); Q2 += __shfl_xor(Q2, 32);
        float mu  = S * (1.f / 256.f);
        float rsg = rsqrtf(Q2 * (1.f / 256.f) - mu * mu + 1e-6f);
        #pragma unroll
        for (int nt = 0; nt < 16; ++nt) {
            float4 gv  = *(const float4*)(c2g  + nt * 16 + lg * 4);
            float4 bev = *(const float4*)(c2be + nt * 16 + lg * 4);
            float4 xv  = *(const float4*)(erow + nt * 16 + lg * 4);
            float g4[4] = { gv.x, gv.y, gv.z, gv.w };
            float e4[4] = { bev.x, bev.y, bev.z, bev.w };
            float x4[4] = { xv.x, xv.y, xv.z, xv.w };
            float pm[4];
            #pragma unroll
            for (int r = 0; r < 4; ++r) {
                float ln = (u1[nt][r] - mu) * rsg * g4[r] + e4[r];
                float sg = 1.f / (1.f + __expf(-ln));
                pm[r] = (float)Ph[nt][r >> 1][r & 1] + 0.5f * sg * x4[r];
            }
            u32x2 wv;
            wv[0] = pk2(pm[0], pm[1]); wv[1] = pk2(pm[2], pm[3]);
            *(u32x2*)(hb + lr * 512 + ((nt * 32 + lg * 8) ^ swz)) = wv;
        }
        #pragma unroll
        for (int ks = 0; ks < 8; ++ks) {
            int k0 = ks * 32 + lg * 8;
            float4 q0v = *(const float4*)(qrow + k0), q1v = *(const float4*)(qrow + k0 + 4);
            u32x4 a;
            a[0] = pk2(q0v.x, q0v.y); a[1] = pk2(q0v.z, q0v.w);
            a[2] = pk2(q1v.x, q1v.y); a[3] = pk2(q1v.z, q1v.w);
            qff[ks] = __builtin_bit_cast(bf16x8, a);
        }
        asm volatile("s_waitcnt lgkmcnt(0)" ::: "memory");
    }
    bf16x8 xfp[8];
    #pragma unroll
    for (int ks = 0; ks < 8; ++ks)
        xfp[ks] = *(const bf16x8*)(hb + lr * 512 + ((ks * 64 + lg * 16) ^ swz));

    // ---------- subs 16..47: gate GEMM, one (nt,half) per sub ----------
    float t0 = 0.f, t1 = 0.f;
    #pragma unroll
    for (int nt = 0; nt < 16; ++nt) {
        f32x4 ga = {};
        #pragma unroll
        for (int half = 0; half < 2; ++half) {
            int s = 16 + nt * 2 + half;
            const char* wb = (const char*)sW[s & 1];
            #pragma unroll
            for (int j = 0; j < 8; ++j) {
                bf16x8 xk = half ? qff[j] : xfp[j];
                bf16x8 wf = *(const bf16x8*)(wb + j * 1024 + l * 16);
                ga = __builtin_amdgcn_mfma_f32_16x16x32_bf16(wf, xk, ga, 0, 0, 0);
            }
            __syncthreads();
            if (s + 2 < 48) stage_sub(wsb, s + 2, sW[s & 1], wid, l);
        }
        float4 gbv = *(const float4*)(gb1 + nt * 16 + lg * 4);
        float4 w0v = *(const float4*)(gw2 + nt * 16 + lg * 4);
        float4 w1v = *(const float4*)(gw2 + 256 + nt * 16 + lg * 4);
        float gb4[4] = { gbv.x, gbv.y, gbv.z, gbv.w };
        float w04[4] = { w0v.x, w0v.y, w0v.z, w0v.w };
        float w14[4] = { w1v.x, w1v.y, w1v.z, w1v.w };
        #pragma unroll
        for (int r = 0; r < 4; ++r) {
            float hv = fmaxf(ga[r] + gb4[r], 0.f);
            t0 += hv * w04[r]; t1 += hv * w14[r];
        }
    }

    // ---------- logits + softmax(2) + store ----------
    t0 += __shfl_xor(t0, 16); t0 += __shfl_xor(t0, 32);
    t1 += __shfl_xor(t1, 16); t1 += __shfl_xor(t1, 32);
    float g0 = 1.f / (1.f + __expf((t1 + gb2[1]) - (t0 + gb2[0])));
    float g1v = 1.f - g0;

    float* orow = out + (size_t)(rowb + lr) * C;
    #pragma unroll
    for (int ks = 0; ks < 8; ++ks) {
        u32x4 pu = __builtin_bit_cast(u32x4, xfp[ks]);
        u32x4 qu = __builtin_bit_cast(u32x4, qff[ks]);
        float4 o0, o1;
        o0.x = bflo(pu[0]) * g0 + bflo(qu[0]) * g1v;
        o0.y = bfhi(pu[0]) * g0 + bfhi(qu[0]) * g1v;
        o0.z = bflo(pu[1]) * g0 + bflo(qu[1]) * g1v;
        o0.w = bfhi(pu[1]) * g0 + bfhi(qu[1]) * g1v;
        o1.x = bflo(pu[2]) * g0 + bflo(qu[2]) * g1v;
        o1.y = bfhi(pu[2]) * g0 + bfhi(qu[2]) * g1v;
        o1.z = bflo(pu[3]) * g0 + bflo(qu[3]) * g1v;
        o1.w = bfhi(pu[3]) * g0 + bfhi(qu[3]) * g1v;
        *(float4*)(orow + ks * 32 + lg * 8)     = o0;
        *(float4*)(orow + ks * 32 + lg * 8 + 4) = o1;
    }
}

extern "C" void kernel_launch(void* const* d_in, const int* in_sizes, int n_in,
                              void* d_out, int out_size, void* d_ws, size_t ws_size,
                              hipStream_t stream) {
    const float* feat  = (const float*)d_in[0];
    const float* qbox  = (const float*)d_in[1];
    const float* qfeat = (const float*)d_in[2];
    const float* posf  = (const float*)d_in[3];
    const float* c1w1  = (const float*)d_in[4];
    const float* c1b1  = (const float*)d_in[5];
    const float* c1w2  = (const float*)d_in[6];
    const float* c1b2  = (const float*)d_in[7];
    const float* c1g   = (const float*)d_in[8];
    const float* c1be  = (const float*)d_in[9];
    const float* c2w1  = (const float*)d_in[10];
    const float* c2b1  = (const float*)d_in[11];
    const float* c2w2  = (const float*)d_in[12];
    const float* c2b2  = (const float*)d_in[13];
    const float* c2g   = (const float*)d_in[14];
    const float* c2be  = (const float*)d_in[15];
    const float* gw1   = (const float*)d_in[16];
    const float* gb1   = (const float*)d_in[17];
    const float* gw2   = (const float*)d_in[18];
    const float* gb2   = (const float*)d_in[19];
    float* out = (float*)d_out;
    unsigned short* wsb = (unsigned short*)d_ws;   // 393216 B used

    prep_weights<<<96, 256, 0, stream>>>(c1w1, c2w1, c1w2, c2w2, gw1, wsb);

    dim3 grid((NB * NQ) / 32), block(128);         // 2048 blocks, 2 waves, 16 rows/wave
    semalign_v12<<<grid, block, 0, stream>>>(
        feat, qbox, qfeat, posf,
        c1b1, c1b2, c1g, c1be,
        c2b1, c2b2, c2g, c2be,
        gb1, gw2, gb2, wsb, out);
}

// Round 13
// 176.426 us; speedup vs baseline: 1.7069x; 1.7069x over previous
//
#include <hip/hip_runtime.h>
#include <hip/hip_bf16.h>
#include <math.h>

typedef __attribute__((ext_vector_type(8))) short bf16x8;
typedef __attribute__((ext_vector_type(4))) float f32x4;
typedef __attribute__((ext_vector_type(2))) __fp16 f16x2;
typedef __attribute__((ext_vector_type(4))) unsigned int u32x4;
typedef __attribute__((ext_vector_type(2))) unsigned int u32x2;

constexpr int NB = 16, NQ = 4096, LF = 2048, C = 256;

__device__ __forceinline__ unsigned short bfbits(float x) {
    return __builtin_bit_cast(unsigned short, __float2bfloat16(x));
}
__device__ __forceinline__ unsigned pk2(float a, float b) {
    return (unsigned)bfbits(a) | ((unsigned)bfbits(b) << 16);
}
__device__ __forceinline__ float bflo(unsigned d) { return __builtin_bit_cast(float, d << 16); }
__device__ __forceinline__ float bfhi(unsigned d) { return __builtin_bit_cast(float, d & 0xffff0000u); }
__device__ __forceinline__ unsigned pkh(float a, float b) {
    f16x2 h = __builtin_amdgcn_cvt_pkrtz(a, b);
    return __builtin_bit_cast(unsigned, h);
}
__device__ __forceinline__ float hlo(unsigned u) {
    f16x2 h = __builtin_bit_cast(f16x2, u); return (float)h[0];
}
__device__ __forceinline__ float hhi(unsigned u) {
    f16x2 h = __builtin_bit_cast(f16x2, u); return (float)h[1];
}

// ---- prep: weights -> bf16 fragment-linear layout in ws (R4-verified) ----
__global__ void prep_weights(const float* __restrict__ c1w1, const float* __restrict__ c2w1,
                             const float* __restrict__ c1w2, const float* __restrict__ c2w2,
                             const float* __restrict__ gw1, unsigned short* __restrict__ ws)
{
    int t = blockIdx.x * 256 + threadIdx.x;          // 0..24575
    const float* src; int K, nks, dstoff, f;
    if (t < 2048)      { src = c1w1; K = 256; nks = 8;  dstoff = 0;      f = t; }
    else if (t < 4096) { src = c2w1; K = 256; nks = 8;  dstoff = 16384;  f = t - 2048; }
    else if (t < 6144) { src = c1w2; K = 64;  nks = 2;  dstoff = 32768;  f = t - 4096; }
    else if (t < 8192) { src = c2w2; K = 64;  nks = 2;  dstoff = 49152;  f = t - 6144; }
    else               { src = gw1;  K = 512; nks = 16; dstoff = 65536;  f = t - 8192; }
    int l = f & 63, s = f >> 6;
    int nt = s / nks, ks = s % nks;
    int n  = nt * 16 + (l & 15);
    int k0 = ks * 32 + (l >> 4) * 8;
    unsigned short* d = ws + dstoff + (size_t)f * 8;
    const float* sp = src + (size_t)n * K + k0;
    #pragma unroll
    for (int e = 0; e < 8; ++e) d[e] = bfbits(sp[e]);
}

// ---- main: v11 structure; GEMM2 split into 2 halves + fp16 LDS stash -> <=128 regs ----
__global__ __launch_bounds__(256, 4)
void semalign_v13(const float* __restrict__ feat,  const float* __restrict__ qbox,
                  const float* __restrict__ qfeat, const float* __restrict__ posf,
                  const float* __restrict__ c1b1,  const float* __restrict__ c1b2,
                  const float* __restrict__ c1g,   const float* __restrict__ c1be,
                  const float* __restrict__ c2b1,  const float* __restrict__ c2b2,
                  const float* __restrict__ c2g,   const float* __restrict__ c2be,
                  const float* __restrict__ gb1,   const float* __restrict__ gw2,
                  const float* __restrict__ gb2,
                  const unsigned short* __restrict__ wsb,
                  float* __restrict__ out)
{
    // per-wave 8 KiB region: H0 at +0 (2K), H1 at +2048 (2K), u-stash at +4096 (4K);
    // pooled overwrites the whole region at the end (all prior contents consumed).
    __shared__ __align__(16) unsigned short sP[4][16][256];

    const int tid = threadIdx.x, l = tid & 63, wid = tid >> 6;
    const int lr = l & 15, lg = l >> 4;
    const int rowb = blockIdx.x * 64 + wid * 16;
    const int q = rowb >> 4;
    const int b = lr;
    const int swz = (lr & 7) << 4;

    const float* prow = posf  + ((size_t)b * NQ + q) * C;
    const float* qrow = qfeat + ((size_t)b * NQ + q) * C;
    float cx = qbox[((size_t)b * NQ + q) * 2 + 0];
    float w  = qbox[((size_t)b * NQ + q) * 2 + 1];
    float fs = fminf(fmaxf((cx - 0.5f * w) * (float)LF, 0.f), (float)(LF - 1));
    float fe = fminf(fmaxf((cx + 0.5f * w) * (float)LF, 0.f), (float)(LF - 1));
    const float* srow = feat + ((size_t)b * LF + (int)rintf(fs)) * C;
    const float* erow = feat + ((size_t)b * LF + (int)rintf(fe)) * C;

    // ---------- phase 0: activation B-frags directly from global ----------
    bf16x8 v1f[8], v2f[8];
    #pragma unroll
    for (int ks = 0; ks < 8; ++ks) {
        int k0 = ks * 32 + lg * 8;
        float4 s0 = *(const float4*)(srow + k0), s1 = *(const float4*)(srow + k0 + 4);
        float4 e0 = *(const float4*)(erow + k0), e1 = *(const float4*)(erow + k0 + 4);
        float4 p0 = *(const float4*)(prow + k0), p1 = *(const float4*)(prow + k0 + 4);
        u32x4 a, c;
        a[0] = pk2(s0.x * p0.x, s0.y * p0.y); a[1] = pk2(s0.z * p0.z, s0.w * p0.w);
        a[2] = pk2(s1.x * p1.x, s1.y * p1.y); a[3] = pk2(s1.z * p1.z, s1.w * p1.w);
        c[0] = pk2(e0.x * p0.x, e0.y * p0.y); c[1] = pk2(e0.z * p0.z, e0.w * p0.w);
        c[2] = pk2(e1.x * p1.x, e1.y * p1.y); c[3] = pk2(e1.z * p1.z, e1.w * p1.w);
        v1f[ks] = __builtin_bit_cast(bf16x8, a);
        v2f[ks] = __builtin_bit_cast(bf16x8, c);
    }

    // ---------- GEMM1 (both contrasts interleaved) ----------
    char* pb = (char*)&sP[wid][0][0];
    {
        f32x4 a1[4] = {}, a2[4] = {};
        #pragma unroll
        for (int ks = 0; ks < 8; ++ks) {
            #pragma unroll
            for (int nt = 0; nt < 4; ++nt) {
                bf16x8 wA = *(const bf16x8*)(wsb + ((size_t)((nt * 8 + ks) * 64 + l)) * 8);
                bf16x8 wB = *(const bf16x8*)(wsb + 16384 + ((size_t)((nt * 8 + ks) * 64 + l)) * 8);
                a1[nt] = __builtin_amdgcn_mfma_f32_16x16x32_bf16(wA, v1f[ks], a1[nt], 0, 0, 0);
                a2[nt] = __builtin_amdgcn_mfma_f32_16x16x32_bf16(wB, v2f[ks], a2[nt], 0, 0, 0);
            }
        }
        #pragma unroll
        for (int nt = 0; nt < 4; ++nt) {
            float4 b1v = *(const float4*)(c1b1 + nt * 16 + lg * 4);
            float4 b2v = *(const float4*)(c2b1 + nt * 16 + lg * 4);
            u32x2 wv;
            wv[0] = pk2(fmaxf(a1[nt][0] + b1v.x, 0.f), fmaxf(a1[nt][1] + b1v.y, 0.f));
            wv[1] = pk2(fmaxf(a1[nt][2] + b1v.z, 0.f), fmaxf(a1[nt][3] + b1v.w, 0.f));
            *(u32x2*)(pb + lr * 128 + ((nt * 32 + lg * 8) ^ swz)) = wv;
            wv[0] = pk2(fmaxf(a2[nt][0] + b2v.x, 0.f), fmaxf(a2[nt][1] + b2v.y, 0.f));
            wv[1] = pk2(fmaxf(a2[nt][2] + b2v.z, 0.f), fmaxf(a2[nt][3] + b2v.w, 0.f));
            *(u32x2*)(pb + 2048 + lr * 128 + ((nt * 32 + lg * 8) ^ swz)) = wv;
        }
    }

    // ---------- GEMM2 + LN + sigmoid + pooled, halved accumulator (32 AGPR peak) ----------
    f16x2 Ph[16][2];
    #pragma unroll
    for (int j = 0; j < 2; ++j) {
        char* hb = pb + j * 2048;
        asm volatile("s_waitcnt lgkmcnt(0)" ::: "memory");
        bf16x8 hf0 = *(const bf16x8*)(hb + lr * 128 + ((0 + lg * 16) ^ swz));
        bf16x8 hf1 = *(const bf16x8*)(hb + lr * 128 + ((64 + lg * 16) ^ swz));
        const unsigned short* w2b = wsb + (j ? 49152 : 32768);
        const float* b2p = j ? c2b2 : c1b2;
        const float* gp  = j ? c2g  : c1g;
        const float* bep = j ? c2be : c1be;
        const float* xrow = j ? erow : srow;
        float S = 0.f, Q2 = 0.f;

        // half 0: nt 0..7 -> bias+stats -> fp16 stash in LDS (pb+4096)
        {
            f32x4 u8[8] = {};
            #pragma unroll
            for (int nt = 0; nt < 8; ++nt) {
                bf16x8 wA = *(const bf16x8*)(w2b + ((size_t)((nt * 2 + 0) * 64 + l)) * 8);
                bf16x8 wB = *(const bf16x8*)(w2b + ((size_t)((nt * 2 + 1) * 64 + l)) * 8);
                u8[nt] = __builtin_amdgcn_mfma_f32_16x16x32_bf16(wA, hf0, u8[nt], 0, 0, 0);
                u8[nt] = __builtin_amdgcn_mfma_f32_16x16x32_bf16(wB, hf1, u8[nt], 0, 0, 0);
            }
            #pragma unroll
            for (int nt = 0; nt < 8; ++nt) {
                float4 bv = *(const float4*)(b2p + nt * 16 + lg * 4);
                u8[nt][0] += bv.x; u8[nt][1] += bv.y; u8[nt][2] += bv.z; u8[nt][3] += bv.w;
                S  += u8[nt][0] + u8[nt][1] + u8[nt][2] + u8[nt][3];
                Q2 += u8[nt][0] * u8[nt][0] + u8[nt][1] * u8[nt][1]
                    + u8[nt][2] * u8[nt][2] + u8[nt][3] * u8[nt][3];
                u32x2 wv;
                wv[0] = pkh(u8[nt][0], u8[nt][1]);
                wv[1] = pkh(u8[nt][2], u8[nt][3]);
                *(u32x2*)(pb + 4096 + nt * 512 + l * 8) = wv;
            }
        }
        // half 1: nt 8..15 kept in AGPRs
        f32x4 u8b[8] = {};
        #pragma unroll
        for (int nt = 0; nt < 8; ++nt) {
            bf16x8 wA = *(const bf16x8*)(w2b + ((size_t)(((nt + 8) * 2 + 0) * 64 + l)) * 8);
            bf16x8 wB = *(const bf16x8*)(w2b + ((size_t)(((nt + 8) * 2 + 1) * 64 + l)) * 8);
            u8b[nt] = __builtin_amdgcn_mfma_f32_16x16x32_bf16(wA, hf0, u8b[nt], 0, 0, 0);
            u8b[nt] = __builtin_amdgcn_mfma_f32_16x16x32_bf16(wB, hf1, u8b[nt], 0, 0, 0);
        }
        #pragma unroll
        for (int nt = 0; nt < 8; ++nt) {
            float4 bv = *(const float4*)(b2p + (nt + 8) * 16 + lg * 4);
            u8b[nt][0] += bv.x; u8b[nt][1] += bv.y; u8b[nt][2] += bv.z; u8b[nt][3] += bv.w;
            S  += u8b[nt][0] + u8b[nt][1] + u8b[nt][2] + u8b[nt][3];
            Q2 += u8b[nt][0] * u8b[nt][0] + u8b[nt][1] * u8b[nt][1]
                + u8b[nt][2] * u8b[nt][2] + u8b[nt][3] * u8b[nt][3];
        }
        S  += __shfl_xor(S, 16);  S  += __shfl_xor(S, 32);
        Q2 += __shfl_xor(Q2, 16); Q2 += __shfl_xor(Q2, 32);
        float mu  = S * (1.f / 256.f);
        float rsg = rsqrtf(Q2 * (1.f / 256.f) - mu * mu + 1e-6f);

        // read back stash BEFORE any pooled write (j=1 writes overwrite stash region)
        u32x2 st[8];
        asm volatile("s_waitcnt lgkmcnt(0)" ::: "memory");
        #pragma unroll
        for (int nt = 0; nt < 8; ++nt)
            st[nt] = *(const u32x2*)(pb + 4096 + nt * 512 + l * 8);
        asm volatile("s_waitcnt lgkmcnt(0)" ::: "memory");

        #pragma unroll
        for (int nt = 0; nt < 16; ++nt) {
            float u4[4];
            if (nt < 8) {
                u4[0] = hlo(st[nt][0]); u4[1] = hhi(st[nt][0]);
                u4[2] = hlo(st[nt][1]); u4[3] = hhi(st[nt][1]);
            } else {
                u4[0] = u8b[nt - 8][0]; u4[1] = u8b[nt - 8][1];
                u4[2] = u8b[nt - 8][2]; u4[3] = u8b[nt - 8][3];
            }
            float4 gv  = *(const float4*)(gp  + nt * 16 + lg * 4);
            float4 bev = *(const float4*)(bep + nt * 16 + lg * 4);
            float4 xv  = *(const float4*)(xrow + nt * 16 + lg * 4);
            float g4[4] = { gv.x, gv.y, gv.z, gv.w };
            float e4[4] = { bev.x, bev.y, bev.z, bev.w };
            float x4[4] = { xv.x, xv.y, xv.z, xv.w };
            float tm[4];
            #pragma unroll
            for (int r = 0; r < 4; ++r) {
                float ln = (u4[r] - mu) * rsg * g4[r] + e4[r];
                float sg = 1.f / (1.f + __expf(-ln));
                tm[r] = 0.5f * sg * x4[r];
            }
            if (j == 0) {
                Ph[nt][0] = __builtin_amdgcn_cvt_pkrtz(tm[0], tm[1]);
                Ph[nt][1] = __builtin_amdgcn_cvt_pkrtz(tm[2], tm[3]);
            } else {
                float p0 = (float)Ph[nt][0][0] + tm[0];
                float p1 = (float)Ph[nt][0][1] + tm[1];
                float p2 = (float)Ph[nt][1][0] + tm[2];
                float p3 = (float)Ph[nt][1][1] + tm[3];
                u32x2 wv;
                wv[0] = pk2(p0, p1); wv[1] = pk2(p2, p3);
                *(u32x2*)(pb + lr * 512 + ((nt * 32 + lg * 8) ^ swz)) = wv;
            }
        }
    }

    // ---------- gate GEMM B-frags: pooled (LDS) + qf (global) ----------
    bf16x8 xf[16];
    asm volatile("s_waitcnt lgkmcnt(0)" ::: "memory");
    #pragma unroll
    for (int ks = 0; ks < 8; ++ks)
        xf[ks] = *(const bf16x8*)(pb + lr * 512 + ((ks * 64 + lg * 16) ^ swz));
    #pragma unroll
    for (int ks = 0; ks < 8; ++ks) {
        int k0 = ks * 32 + lg * 8;
        float4 q0 = *(const float4*)(qrow + k0), q1 = *(const float4*)(qrow + k0 + 4);
        u32x4 a;
        a[0] = pk2(q0.x, q0.y); a[1] = pk2(q0.z, q0.w);
        a[2] = pk2(q1.x, q1.y); a[3] = pk2(q1.z, q1.w);
        xf[8 + ks] = __builtin_bit_cast(bf16x8, a);
    }

    // ---------- gate GEMM + logits ----------
    float t0 = 0.f, t1 = 0.f;
    const unsigned short* gwb = wsb + 65536;
    for (int ntp = 0; ntp < 8; ++ntp) {
        f32x4 ga0 = {}, ga1 = {};
        int n0 = ntp * 2, n1 = ntp * 2 + 1;
        #pragma unroll
        for (int kk = 0; kk < 16; ++kk) {
            bf16x8 wA = *(const bf16x8*)(gwb + ((size_t)((n0 * 16 + kk) * 64 + l)) * 8);
            bf16x8 wB = *(const bf16x8*)(gwb + ((size_t)((n1 * 16 + kk) * 64 + l)) * 8);
            ga0 = __builtin_amdgcn_mfma_f32_16x16x32_bf16(wA, xf[kk], ga0, 0, 0, 0);
            ga1 = __builtin_amdgcn_mfma_f32_16x16x32_bf16(wB, xf[kk], ga1, 0, 0, 0);
        }
        #pragma unroll
        for (int t = 0; t < 2; ++t) {
            f32x4 ga = t ? ga1 : ga0;
            int nt = ntp * 2 + t;
            float4 gbv = *(const float4*)(gb1 + nt * 16 + lg * 4);
            float4 w0v = *(const float4*)(gw2 + nt * 16 + lg * 4);
            float4 w1v = *(const float4*)(gw2 + 256 + nt * 16 + lg * 4);
            float gb4[4] = { gbv.x, gbv.y, gbv.z, gbv.w };
            float w04[4] = { w0v.x, w0v.y, w0v.z, w0v.w };
            float w14[4] = { w1v.x, w1v.y, w1v.z, w1v.w };
            #pragma unroll
            for (int r = 0; r < 4; ++r) {
                float hv = fmaxf(ga[r] + gb4[r], 0.f);
                t0 += hv * w04[r]; t1 += hv * w14[r];
            }
        }
    }
    t0 += __shfl_xor(t0, 16); t0 += __shfl_xor(t0, 32);
    t1 += __shfl_xor(t1, 16); t1 += __shfl_xor(t1, 32);
    float g0 = 1.f / (1.f + __expf((t1 + gb2[1]) - (t0 + gb2[0])));
    float g1 = 1.f - g0;

    // ---------- epilogue ----------
    float* orow = out + (size_t)(rowb + lr) * C;
    #pragma unroll
    for (int ks = 0; ks < 8; ++ks) {
        u32x4 pu = __builtin_bit_cast(u32x4, xf[ks]);
        u32x4 qu = __builtin_bit_cast(u32x4, xf[8 + ks]);
        float4 o0, o1;
        o0.x = bflo(pu[0]) * g0 + bflo(qu[0]) * g1;
        o0.y = bfhi(pu[0]) * g0 + bfhi(qu[0]) * g1;
        o0.z = bflo(pu[1]) * g0 + bflo(qu[1]) * g1;
        o0.w = bfhi(pu[1]) * g0 + bfhi(qu[1]) * g1;
        o1.x = bflo(pu[2]) * g0 + bflo(qu[2]) * g1;
        o1.y = bfhi(pu[2]) * g0 + bfhi(qu[2]) * g1;
        o1.z = bflo(pu[3]) * g0 + bflo(qu[3]) * g1;
        o1.w = bfhi(pu[3]) * g0 + bfhi(qu[3]) * g1;
        *(float4*)(orow + ks * 32 + lg * 8)     = o0;
        *(float4*)(orow + ks * 32 + lg * 8 + 4) = o1;
    }
}

extern "C" void kernel_launch(void* const* d_in, const int* in_sizes, int n_in,
                              void* d_out, int out_size, void* d_ws, size_t ws_size,
                              hipStream_t stream) {
    const float* feat  = (const float*)d_in[0];
    const float* qbox  = (const float*)d_in[1];
    const float* qfeat = (const float*)d_in[2];
    const float* posf  = (const float*)d_in[3];
    const float* c1w1  = (const float*)d_in[4];
    const float* c1b1  = (const float*)d_in[5];
    const float* c1w2  = (const float*)d_in[6];
    const float* c1b2  = (const float*)d_in[7];
    const float* c1g   = (const float*)d_in[8];
    const float* c1be  = (const float*)d_in[9];
    const float* c2w1  = (const float*)d_in[10];
    const float* c2b1  = (const float*)d_in[11];
    const float* c2w2  = (const float*)d_in[12];
    const float* c2b2  = (const float*)d_in[13];
    const float* c2g   = (const float*)d_in[14];
    const float* c2be  = (const float*)d_in[15];
    const float* gw1   = (const float*)d_in[16];
    const float* gb1   = (const float*)d_in[17];
    const float* gw2   = (const float*)d_in[18];
    const float* gb2   = (const float*)d_in[19];
    float* out = (float*)d_out;
    unsigned short* wsb = (unsigned short*)d_ws;   // 393216 B used

    prep_weights<<<96, 256, 0, stream>>>(c1w1, c2w1, c1w2, c2w2, gw1, wsb);

    dim3 grid((NB * NQ) / 64), block(256);         // 1024 blocks, 4 waves, 16 rows/wave
    semalign_v13<<<grid, block, 0, stream>>>(
        feat, qbox, qfeat, posf,
        c1b1, c1b2, c1g, c1be,
        c2b1, c2b2, c2g, c2be,
        gb1, gw2, gb2, wsb, out);
}

// Round 14
// 164.058 us; speedup vs baseline: 1.8356x; 1.0754x over previous
//
#include <hip/hip_runtime.h>
#include <hip/hip_bf16.h>
#include <math.h>

typedef __attribute__((ext_vector_type(8))) short bf16x8;
typedef __attribute__((ext_vector_type(4))) float f32x4;
typedef __attribute__((ext_vector_type(2))) __fp16 f16x2;
typedef __attribute__((ext_vector_type(4))) unsigned int u32x4;
typedef __attribute__((ext_vector_type(2))) unsigned int u32x2;

constexpr int NB = 16, NQ = 4096, LF = 2048, C = 256;

__device__ __forceinline__ unsigned short bfbits(float x) {
    return __builtin_bit_cast(unsigned short, __float2bfloat16(x));
}
__device__ __forceinline__ unsigned pk2(float a, float b) {
    return (unsigned)bfbits(a) | ((unsigned)bfbits(b) << 16);
}
__device__ __forceinline__ float bflo(unsigned d) { return __builtin_bit_cast(float, d << 16); }
__device__ __forceinline__ float bfhi(unsigned d) { return __builtin_bit_cast(float, d & 0xffff0000u); }
__device__ __forceinline__ unsigned pkh(float a, float b) {
    f16x2 h = __builtin_amdgcn_cvt_pkrtz(a, b);
    return __builtin_bit_cast(unsigned, h);
}
__device__ __forceinline__ float hlo(unsigned u) {
    f16x2 h = __builtin_bit_cast(f16x2, u); return (float)h[0];
}
__device__ __forceinline__ float hhi(unsigned u) {
    f16x2 h = __builtin_bit_cast(f16x2, u); return (float)h[1];
}

// ---- prep: weights -> bf16 fragment-linear layout in ws (R4-verified) ----
__global__ void prep_weights(const float* __restrict__ c1w1, const float* __restrict__ c2w1,
                             const float* __restrict__ c1w2, const float* __restrict__ c2w2,
                             const float* __restrict__ gw1, unsigned short* __restrict__ ws)
{
    int t = blockIdx.x * 256 + threadIdx.x;          // 0..24575
    const float* src; int K, nks, dstoff, f;
    if (t < 2048)      { src = c1w1; K = 256; nks = 8;  dstoff = 0;      f = t; }
    else if (t < 4096) { src = c2w1; K = 256; nks = 8;  dstoff = 16384;  f = t - 2048; }
    else if (t < 6144) { src = c1w2; K = 64;  nks = 2;  dstoff = 32768;  f = t - 4096; }
    else if (t < 8192) { src = c2w2; K = 64;  nks = 2;  dstoff = 49152;  f = t - 6144; }
    else               { src = gw1;  K = 512; nks = 16; dstoff = 65536;  f = t - 8192; }
    int l = f & 63, s = f >> 6;
    int nt = s / nks, ks = s % nks;
    int n  = nt * 16 + (l & 15);
    int k0 = ks * 32 + (l >> 4) * 8;
    unsigned short* d = ws + dstoff + (size_t)f * 8;
    const float* sp = src + (size_t)n * K + k0;
    #pragma unroll
    for (int e = 0; e < 8; ++e) d[e] = bfbits(sp[e]);
}

// ---- main: R13 + gate loop transposed (ga[16] in AGPR, 1 live x-frag) ----
__global__ __launch_bounds__(256, 4)
void semalign_v14(const float* __restrict__ feat,  const float* __restrict__ qbox,
                  const float* __restrict__ qfeat, const float* __restrict__ posf,
                  const float* __restrict__ c1b1,  const float* __restrict__ c1b2,
                  const float* __restrict__ c1g,   const float* __restrict__ c1be,
                  const float* __restrict__ c2b1,  const float* __restrict__ c2b2,
                  const float* __restrict__ c2g,   const float* __restrict__ c2be,
                  const float* __restrict__ gb1,   const float* __restrict__ gw2,
                  const float* __restrict__ gb2,
                  const unsigned short* __restrict__ wsb,
                  float* __restrict__ out)
{
    // per-wave 8 KiB region: H0 at +0 (2K), H1 at +2048 (2K), u-stash at +4096 (4K);
    // pooled overwrites the whole region at the end (all prior contents consumed).
    __shared__ __align__(16) unsigned short sP[4][16][256];

    const int tid = threadIdx.x, l = tid & 63, wid = tid >> 6;
    const int lr = l & 15, lg = l >> 4;
    const int rowb = blockIdx.x * 64 + wid * 16;
    const int q = rowb >> 4;
    const int b = lr;
    const int swz = (lr & 7) << 4;

    const float* prow = posf  + ((size_t)b * NQ + q) * C;
    const float* qrow = qfeat + ((size_t)b * NQ + q) * C;
    float cx = qbox[((size_t)b * NQ + q) * 2 + 0];
    float w  = qbox[((size_t)b * NQ + q) * 2 + 1];
    float fs = fminf(fmaxf((cx - 0.5f * w) * (float)LF, 0.f), (float)(LF - 1));
    float fe = fminf(fmaxf((cx + 0.5f * w) * (float)LF, 0.f), (float)(LF - 1));
    const float* srow = feat + ((size_t)b * LF + (int)rintf(fs)) * C;
    const float* erow = feat + ((size_t)b * LF + (int)rintf(fe)) * C;

    // ---------- phase 0: activation B-frags directly from global ----------
    bf16x8 v1f[8], v2f[8];
    #pragma unroll
    for (int ks = 0; ks < 8; ++ks) {
        int k0 = ks * 32 + lg * 8;
        float4 s0 = *(const float4*)(srow + k0), s1 = *(const float4*)(srow + k0 + 4);
        float4 e0 = *(const float4*)(erow + k0), e1 = *(const float4*)(erow + k0 + 4);
        float4 p0 = *(const float4*)(prow + k0), p1 = *(const float4*)(prow + k0 + 4);
        u32x4 a, c;
        a[0] = pk2(s0.x * p0.x, s0.y * p0.y); a[1] = pk2(s0.z * p0.z, s0.w * p0.w);
        a[2] = pk2(s1.x * p1.x, s1.y * p1.y); a[3] = pk2(s1.z * p1.z, s1.w * p1.w);
        c[0] = pk2(e0.x * p0.x, e0.y * p0.y); c[1] = pk2(e0.z * p0.z, e0.w * p0.w);
        c[2] = pk2(e1.x * p1.x, e1.y * p1.y); c[3] = pk2(e1.z * p1.z, e1.w * p1.w);
        v1f[ks] = __builtin_bit_cast(bf16x8, a);
        v2f[ks] = __builtin_bit_cast(bf16x8, c);
    }

    // ---------- GEMM1 (both contrasts interleaved) ----------
    char* pb = (char*)&sP[wid][0][0];
    {
        f32x4 a1[4] = {}, a2[4] = {};
        #pragma unroll
        for (int ks = 0; ks < 8; ++ks) {
            #pragma unroll
            for (int nt = 0; nt < 4; ++nt) {
                bf16x8 wA = *(const bf16x8*)(wsb + ((size_t)((nt * 8 + ks) * 64 + l)) * 8);
                bf16x8 wB = *(const bf16x8*)(wsb + 16384 + ((size_t)((nt * 8 + ks) * 64 + l)) * 8);
                a1[nt] = __builtin_amdgcn_mfma_f32_16x16x32_bf16(wA, v1f[ks], a1[nt], 0, 0, 0);
                a2[nt] = __builtin_amdgcn_mfma_f32_16x16x32_bf16(wB, v2f[ks], a2[nt], 0, 0, 0);
            }
        }
        #pragma unroll
        for (int nt = 0; nt < 4; ++nt) {
            float4 b1v = *(const float4*)(c1b1 + nt * 16 + lg * 4);
            float4 b2v = *(const float4*)(c2b1 + nt * 16 + lg * 4);
            u32x2 wv;
            wv[0] = pk2(fmaxf(a1[nt][0] + b1v.x, 0.f), fmaxf(a1[nt][1] + b1v.y, 0.f));
            wv[1] = pk2(fmaxf(a1[nt][2] + b1v.z, 0.f), fmaxf(a1[nt][3] + b1v.w, 0.f));
            *(u32x2*)(pb + lr * 128 + ((nt * 32 + lg * 8) ^ swz)) = wv;
            wv[0] = pk2(fmaxf(a2[nt][0] + b2v.x, 0.f), fmaxf(a2[nt][1] + b2v.y, 0.f));
            wv[1] = pk2(fmaxf(a2[nt][2] + b2v.z, 0.f), fmaxf(a2[nt][3] + b2v.w, 0.f));
            *(u32x2*)(pb + 2048 + lr * 128 + ((nt * 32 + lg * 8) ^ swz)) = wv;
        }
    }

    // ---------- GEMM2 + LN + sigmoid + pooled, halved accumulator (R13-verified) ----------
    f16x2 Ph[16][2];
    #pragma unroll
    for (int j = 0; j < 2; ++j) {
        char* hb = pb + j * 2048;
        asm volatile("s_waitcnt lgkmcnt(0)" ::: "memory");
        bf16x8 hf0 = *(const bf16x8*)(hb + lr * 128 + ((0 + lg * 16) ^ swz));
        bf16x8 hf1 = *(const bf16x8*)(hb + lr * 128 + ((64 + lg * 16) ^ swz));
        const unsigned short* w2b = wsb + (j ? 49152 : 32768);
        const float* b2p = j ? c2b2 : c1b2;
        const float* gp  = j ? c2g  : c1g;
        const float* bep = j ? c2be : c1be;
        const float* xrow = j ? erow : srow;
        float S = 0.f, Q2 = 0.f;

        // half 0: nt 0..7 -> bias+stats -> fp16 stash in LDS (pb+4096)
        {
            f32x4 u8[8] = {};
            #pragma unroll
            for (int nt = 0; nt < 8; ++nt) {
                bf16x8 wA = *(const bf16x8*)(w2b + ((size_t)((nt * 2 + 0) * 64 + l)) * 8);
                bf16x8 wB = *(const bf16x8*)(w2b + ((size_t)((nt * 2 + 1) * 64 + l)) * 8);
                u8[nt] = __builtin_amdgcn_mfma_f32_16x16x32_bf16(wA, hf0, u8[nt], 0, 0, 0);
                u8[nt] = __builtin_amdgcn_mfma_f32_16x16x32_bf16(wB, hf1, u8[nt], 0, 0, 0);
            }
            #pragma unroll
            for (int nt = 0; nt < 8; ++nt) {
                float4 bv = *(const float4*)(b2p + nt * 16 + lg * 4);
                u8[nt][0] += bv.x; u8[nt][1] += bv.y; u8[nt][2] += bv.z; u8[nt][3] += bv.w;
                S  += u8[nt][0] + u8[nt][1] + u8[nt][2] + u8[nt][3];
                Q2 += u8[nt][0] * u8[nt][0] + u8[nt][1] * u8[nt][1]
                    + u8[nt][2] * u8[nt][2] + u8[nt][3] * u8[nt][3];
                u32x2 wv;
                wv[0] = pkh(u8[nt][0], u8[nt][1]);
                wv[1] = pkh(u8[nt][2], u8[nt][3]);
                *(u32x2*)(pb + 4096 + nt * 512 + l * 8) = wv;
            }
        }
        // half 1: nt 8..15 kept in AGPRs
        f32x4 u8b[8] = {};
        #pragma unroll
        for (int nt = 0; nt < 8; ++nt) {
            bf16x8 wA = *(const bf16x8*)(w2b + ((size_t)(((nt + 8) * 2 + 0) * 64 + l)) * 8);
            bf16x8 wB = *(const bf16x8*)(w2b + ((size_t)(((nt + 8) * 2 + 1) * 64 + l)) * 8);
            u8b[nt] = __builtin_amdgcn_mfma_f32_16x16x32_bf16(wA, hf0, u8b[nt], 0, 0, 0);
            u8b[nt] = __builtin_amdgcn_mfma_f32_16x16x32_bf16(wB, hf1, u8b[nt], 0, 0, 0);
        }
        #pragma unroll
        for (int nt = 0; nt < 8; ++nt) {
            float4 bv = *(const float4*)(b2p + (nt + 8) * 16 + lg * 4);
            u8b[nt][0] += bv.x; u8b[nt][1] += bv.y; u8b[nt][2] += bv.z; u8b[nt][3] += bv.w;
            S  += u8b[nt][0] + u8b[nt][1] + u8b[nt][2] + u8b[nt][3];
            Q2 += u8b[nt][0] * u8b[nt][0] + u8b[nt][1] * u8b[nt][1]
                + u8b[nt][2] * u8b[nt][2] + u8b[nt][3] * u8b[nt][3];
        }
        S  += __shfl_xor(S, 16);  S  += __shfl_xor(S, 32);
        Q2 += __shfl_xor(Q2, 16); Q2 += __shfl_xor(Q2, 32);
        float mu  = S * (1.f / 256.f);
        float rsg = rsqrtf(Q2 * (1.f / 256.f) - mu * mu + 1e-6f);

        // read back stash BEFORE any pooled write (j=1 writes overwrite stash region)
        u32x2 st[8];
        asm volatile("s_waitcnt lgkmcnt(0)" ::: "memory");
        #pragma unroll
        for (int nt = 0; nt < 8; ++nt)
            st[nt] = *(const u32x2*)(pb + 4096 + nt * 512 + l * 8);
        asm volatile("s_waitcnt lgkmcnt(0)" ::: "memory");

        #pragma unroll
        for (int nt = 0; nt < 16; ++nt) {
            float u4[4];
            if (nt < 8) {
                u4[0] = hlo(st[nt][0]); u4[1] = hhi(st[nt][0]);
                u4[2] = hlo(st[nt][1]); u4[3] = hhi(st[nt][1]);
            } else {
                u4[0] = u8b[nt - 8][0]; u4[1] = u8b[nt - 8][1];
                u4[2] = u8b[nt - 8][2]; u4[3] = u8b[nt - 8][3];
            }
            float4 gv  = *(const float4*)(gp  + nt * 16 + lg * 4);
            float4 bev = *(const float4*)(bep + nt * 16 + lg * 4);
            float4 xv  = *(const float4*)(xrow + nt * 16 + lg * 4);
            float g4[4] = { gv.x, gv.y, gv.z, gv.w };
            float e4[4] = { bev.x, bev.y, bev.z, bev.w };
            float x4[4] = { xv.x, xv.y, xv.z, xv.w };
            float tm[4];
            #pragma unroll
            for (int r = 0; r < 4; ++r) {
                float ln = (u4[r] - mu) * rsg * g4[r] + e4[r];
                float sg = 1.f / (1.f + __expf(-ln));
                tm[r] = 0.5f * sg * x4[r];
            }
            if (j == 0) {
                Ph[nt][0] = __builtin_amdgcn_cvt_pkrtz(tm[0], tm[1]);
                Ph[nt][1] = __builtin_amdgcn_cvt_pkrtz(tm[2], tm[3]);
            } else {
                float p0 = (float)Ph[nt][0][0] + tm[0];
                float p1 = (float)Ph[nt][0][1] + tm[1];
                float p2 = (float)Ph[nt][1][0] + tm[2];
                float p3 = (float)Ph[nt][1][1] + tm[3];
                u32x2 wv;
                wv[0] = pk2(p0, p1); wv[1] = pk2(p2, p3);
                *(u32x2*)(pb + lr * 512 + ((nt * 32 + lg * 8) ^ swz)) = wv;
            }
        }
    }
    asm volatile("s_waitcnt lgkmcnt(0)" ::: "memory");

    // ---------- gate GEMM, transposed loop: ga[16] in AGPRs, 1 live x-frag ----------
    f32x4 ga[16] = {};
    const unsigned short* gwb = wsb + 65536;
    #pragma clang loop unroll(disable)
    for (int kk = 0; kk < 16; ++kk) {
        bf16x8 xk;
        if (kk < 8) {
            xk = *(const bf16x8*)(pb + lr * 512 + ((kk * 64 + lg * 16) ^ swz));
        } else {
            int k0 = (kk - 8) * 32 + lg * 8;
            float4 q0 = *(const float4*)(qrow + k0), q1 = *(const float4*)(qrow + k0 + 4);
            u32x4 a;
            a[0] = pk2(q0.x, q0.y); a[1] = pk2(q0.z, q0.w);
            a[2] = pk2(q1.x, q1.y); a[3] = pk2(q1.z, q1.w);
            xk = __builtin_bit_cast(bf16x8, a);
        }
        #pragma unroll
        for (int nt = 0; nt < 16; ++nt) {
            bf16x8 wf = *(const bf16x8*)(gwb + ((size_t)((nt * 16 + kk) * 64 + l)) * 8);
            ga[nt] = __builtin_amdgcn_mfma_f32_16x16x32_bf16(wf, xk, ga[nt], 0, 0, 0);
        }
    }

    // ---------- logits + softmax(2) ----------
    float t0 = 0.f, t1 = 0.f;
    #pragma unroll
    for (int nt = 0; nt < 16; ++nt) {
        float4 gbv = *(const float4*)(gb1 + nt * 16 + lg * 4);
        float4 w0v = *(const float4*)(gw2 + nt * 16 + lg * 4);
        float4 w1v = *(const float4*)(gw2 + 256 + nt * 16 + lg * 4);
        float gb4[4] = { gbv.x, gbv.y, gbv.z, gbv.w };
        float w04[4] = { w0v.x, w0v.y, w0v.z, w0v.w };
        float w14[4] = { w1v.x, w1v.y, w1v.z, w1v.w };
        #pragma unroll
        for (int r = 0; r < 4; ++r) {
            float hv = fmaxf(ga[nt][r] + gb4[r], 0.f);
            t0 += hv * w04[r]; t1 += hv * w14[r];
        }
    }
    t0 += __shfl_xor(t0, 16); t0 += __shfl_xor(t0, 32);
    t1 += __shfl_xor(t1, 16); t1 += __shfl_xor(t1, 32);
    float g0 = 1.f / (1.f + __expf((t1 + gb2[1]) - (t0 + gb2[0])));
    float g1 = 1.f - g0;

    // ---------- epilogue: pooled re-read from LDS, qf from global (f32) ----------
    float* orow = out + (size_t)(rowb + lr) * C;
    #pragma unroll
    for (int ks = 0; ks < 8; ++ks) {
        bf16x8 pf = *(const bf16x8*)(pb + lr * 512 + ((ks * 64 + lg * 16) ^ swz));
        u32x4 pu = __builtin_bit_cast(u32x4, pf);
        int k0 = ks * 32 + lg * 8;
        float4 q0 = *(const float4*)(qrow + k0), q1 = *(const float4*)(qrow + k0 + 4);
        float4 o0, o1;
        o0.x = bflo(pu[0]) * g0 + q0.x * g1;
        o0.y = bfhi(pu[0]) * g0 + q0.y * g1;
        o0.z = bflo(pu[1]) * g0 + q0.z * g1;
        o0.w = bfhi(pu[1]) * g0 + q0.w * g1;
        o1.x = bflo(pu[2]) * g0 + q1.x * g1;
        o1.y = bfhi(pu[2]) * g0 + q1.y * g1;
        o1.z = bflo(pu[3]) * g0 + q1.z * g1;
        o1.w = bfhi(pu[3]) * g0 + q1.w * g1;
        *(float4*)(orow + ks * 32 + lg * 8)     = o0;
        *(float4*)(orow + ks * 32 + lg * 8 + 4) = o1;
    }
}

extern "C" void kernel_launch(void* const* d_in, const int* in_sizes, int n_in,
                              void* d_out, int out_size, void* d_ws, size_t ws_size,
                              hipStream_t stream) {
    const float* feat  = (const float*)d_in[0];
    const float* qbox  = (const float*)d_in[1];
    const float* qfeat = (const float*)d_in[2];
    const float* posf  = (const float*)d_in[3];
    const float* c1w1  = (const float*)d_in[4];
    const float* c1b1  = (const float*)d_in[5];
    const float* c1w2  = (const float*)d_in[6];
    const float* c1b2  = (const float*)d_in[7];
    const float* c1g   = (const float*)d_in[8];
    const float* c1be  = (const float*)d_in[9];
    const float* c2w1  = (const float*)d_in[10];
    const float* c2b1  = (const float*)d_in[11];
    const float* c2w2  = (const float*)d_in[12];
    const float* c2b2  = (const float*)d_in[13];
    const float* c2g   = (const float*)d_in[14];
    const float* c2be  = (const float*)d_in[15];
    const float* gw1   = (const float*)d_in[16];
    const float* gb1   = (const float*)d_in[17];
    const float* gw2   = (const float*)d_in[18];
    const float* gb2   = (const float*)d_in[19];
    float* out = (float*)d_out;
    unsigned short* wsb = (unsigned short*)d_ws;   // 393216 B used

    prep_weights<<<96, 256, 0, stream>>>(c1w1, c2w1, c1w2, c2w2, gw1, wsb);

    dim3 grid((NB * NQ) / 64), block(256);         // 1024 blocks, 4 waves, 16 rows/wave
    semalign_v14<<<grid, block, 0, stream>>>(
        feat, qbox, qfeat, posf,
        c1b1, c1b2, c1g, c1be,
        c2b1, c2b2, c2g, c2be,
        gb1, gw2, gb2, wsb, out);
}